// Round 9
// baseline (194.738 us; speedup 1.0000x reference)
//
#include <hip/hip_runtime.h>
#include <hip/hip_bf16.h>
#include <hip/hip_fp16.h>
#include <math.h>

// F_IN=256, H=4, C=32, H*C=128; NEG_SLOPE_ATT=0.2, NEG_SLOPE_ACT=0.01, EPS=1e-5
// bias skipped: batch-stat BatchNorm subtracts it exactly.
//
// R8: bucket-fused agg REGRESSED 774us (latency serialization).
// R9: wave-per-dst agg; fixed-stride buckets. 233us.
// R10: __threadfence per block REGRESSED 1248us (per-XCD L2 wb+inv).
// R11: fence-free fused BN (NC-copy atomics). 206us; agg 45.2.
// R12: DPW=4 killed TLP. R13: waug augmented-GEMM WORKED (~-7us; gemm time
//      tracks VALU count ~1:1 at 1 block/CU). R14: agg loop revert -> 58us:
//      regression was latency serialization via lp/lsrc lgkm ordering.
// R15/16: shfl-pipelined agg (indices in regs, hb2 gathers overlap a_s+exp
//      chain). agg 58 -> 50.0, VALU 51%. 203.9.
// R17: gemm v_cvt_pk_bf16_f32 staging/epilogue + pair_scatter 256 blocks.
//      193.9 (best). agg 48.5 @ VALU 51%, all other kernels < 48.
// R18: hb2 bf16 -> FP16 pairs (v_cvt_pkrtz_f16_f32 in gemm epilogue); agg
//      consumes via __half2float+fmaf so LLVM forms v_fma_mix_f32 (op_sel
//      reads the 16-bit half directly) -> the 16 unpack insts per 8-edge
//      step vanish. fp16 also has 3 more mantissa bits than bf16: absmax
//      should drop ~8x (canary for packing correctness).

typedef __attribute__((ext_vector_type(8))) short bf8_t;   // 8 bf16 in 4 VGPRs
typedef __attribute__((ext_vector_type(4))) float f4_t;    // MFMA accumulator

__device__ inline unsigned short f2bf(float f) {  // RNE fp32->bf16
  unsigned u = __float_as_uint(f);
  u += 0x7fff + ((u >> 16) & 1);
  return (unsigned short)(u >> 16);
}
// packed RNE fp32x2 -> bf16x2 (low = a, high = b); gfx950 has no builtin
__device__ inline unsigned cvtpk(float a, float b) {
  unsigned r;
  asm("v_cvt_pk_bf16_f32 %0, %1, %2" : "=v"(r) : "v"(a), "v"(b));
  return r;
}
// packed RTZ fp32x2 -> fp16x2 (low = a, high = b)
__device__ inline unsigned cvtpk_f16(float a, float b) {
  unsigned r;
  asm("v_cvt_pkrtz_f16_f32 %0, %1, %2" : "=v"(r) : "v"(a), "v"(b));
  return r;
}
__device__ inline float lrelu02(float v) { return v > 0.f ? v : 0.2f * v; }
// fp16 halves of a packed dword -> f32 (compiler folds fpext into v_fma_mix)
__device__ inline float f16lo(unsigned g) {
  return __half2float(__ushort_as_half((unsigned short)(g & 0xffffu)));
}
__device__ inline float f16hi(unsigned g) {
  return __half2float(__ushort_as_half((unsigned short)(g >> 16)));
}

#define LSTRIDE 264   // 256 + 8 bf16 pad
#define PSTRIDE 2048  // per-bucket pairs region (max bucket ~1130 = 32 sigma)
#define SSTRIDE 2112  // PSTRIDE + 64 self-loops
#define NC 32         // BN stat atomic copies

// ---- fold attention vectors into augmented GEMM rows ----
__global__ __launch_bounds__(256) void att_fold_k(const float* __restrict__ w,
                                                  const float* __restrict__ att_s,
                                                  const float* __restrict__ att_d,
                                                  float* __restrict__ waug) {
  int j = blockIdx.x;  // 0..7
  int head = j & 3;
  const float* av = (j < 4 ? att_s : att_d) + head * 32;
  int col = threadIdx.x;
  float s = 0.f;
#pragma unroll
  for (int c = 0; c < 32; c++)
    s += av[c] * w[(size_t)(head * 32 + c) * 256 + col];
  waug[j * 256 + col] = s;
}

// ------- MFMA GEMM + att scores as augmented columns -------
// hb2[node][j] (dword) = ( fp16 h[node][j] , fp16 h[node][j+64] )
// B rows 0-127: W; rows 128-135: waug hi; rows 136-143: waug lo.
__global__ __launch_bounds__(256) void gemm_mfma(const float* __restrict__ x,
                                                 const float* __restrict__ w,
                                                 const float* __restrict__ waug,
                                                 unsigned* __restrict__ hb2,
                                                 float* __restrict__ a_s,
                                                 float* __restrict__ a_d,
                                                 int n, int ntiles) {
  __shared__ unsigned short wsl[144 * LSTRIDE];  // 76.0 KB
  __shared__ unsigned short xsl[64 * LSTRIDE];   // 33.8 KB
  int tid = threadIdx.x;
  int lane = tid & 63;
  int wid = tid >> 6;
  int quad = lane >> 4;
  int l15 = lane & 15;

  // stage W once: 128 rows x 64 float4 = 8192 f4, 32/thread
#pragma unroll 4
  for (int i = 0; i < 32; i++) {
    int idx = tid + i * 256;
    int row = idx >> 6;
    int f4 = idx & 63;
    float4 v = *(const float4*)&w[(size_t)row * 256 + f4 * 4];
    *(uint2*)&wsl[row * LSTRIDE + f4 * 4] =
        make_uint2(cvtpk(v.x, v.y), cvtpk(v.z, v.w));
  }
  // stage waug: 8 rows fp32 -> hi (rows 128-135) + lo (rows 136-143)
#pragma unroll
  for (int i = 0; i < 8; i++) {
    int idx = tid + i * 256;   // 0..2047
    int row = idx >> 8;        // 0..7
    int col = idx & 255;
    float v = waug[idx];
    unsigned short hi = f2bf(v);
    float lov = v - __uint_as_float((unsigned)hi << 16);
    wsl[(128 + row) * LSTRIDE + col] = hi;
    wsl[(136 + row) * LSTRIDE + col] = f2bf(lov);
  }

  float4 pre[16];
  int tile = blockIdx.x;
  if (tile < ntiles) {
#pragma unroll
    for (int i = 0; i < 16; i++) {
      int idx = tid + i * 256;
      int row = idx >> 6, f4 = idx & 63;
      int grow = tile * 64 + row;
      pre[i] = (grow < n) ? *(const float4*)&x[(size_t)grow * 256 + f4 * 4]
                          : make_float4(0.f, 0.f, 0.f, 0.f);
    }
  }

  for (; tile < ntiles; tile += gridDim.x) {
    __syncthreads();
#pragma unroll
    for (int i = 0; i < 16; i++) {
      int idx = tid + i * 256;
      int row = idx >> 6, f4 = idx & 63;
      *(uint2*)&xsl[row * LSTRIDE + f4 * 4] =
          make_uint2(cvtpk(pre[i].x, pre[i].y), cvtpk(pre[i].z, pre[i].w));
    }
    __syncthreads();

    int nxt = tile + gridDim.x;
    if (nxt < ntiles) {
#pragma unroll
      for (int i = 0; i < 16; i++) {
        int idx = tid + i * 256;
        int row = idx >> 6, f4 = idx & 63;
        int grow = nxt * 64 + row;
        pre[i] = (grow < n) ? *(const float4*)&x[(size_t)grow * 256 + f4 * 4]
                            : make_float4(0.f, 0.f, 0.f, 0.f);
      }
    }

    f4_t acc[9];
#pragma unroll
    for (int t = 0; t < 9; t++) acc[t] = (f4_t){0.f, 0.f, 0.f, 0.f};
    const unsigned short* arow = &xsl[(wid * 16 + l15) * LSTRIDE];
#pragma unroll
    for (int ks = 0; ks < 8; ks++) {
      bf8_t af = *(const bf8_t*)&arow[ks * 32 + quad * 8];
#pragma unroll
      for (int t = 0; t < 9; t++) {
        bf8_t bf = *(const bf8_t*)&wsl[(t * 16 + l15) * LSTRIDE + ks * 32 + quad * 8];
        acc[t] = __builtin_amdgcn_mfma_f32_16x16x32_bf16(af, bf, acc[t], 0, 0, 0);
      }
    }

    // C/D layout: col = lane&15 (-> t*16+l15), row = quad*4 + reg  [m89-verified]
    int growb = tile * 64 + wid * 16 + quad * 4;
#pragma unroll
    for (int r = 0; r < 4; r++) {
      int grow = growb + r;
      bool ok = grow < n;
      if (ok) {
        unsigned* orow = &hb2[(size_t)grow * 64];
#pragma unroll
        for (int t = 0; t < 4; t++)
          orow[t * 16 + l15] = cvtpk_f16(acc[t][r], acc[t + 4][r]);
      }
      // att columns: lane l15<8 holds hi(col l15); lane l15+8 holds lo
      float v8 = acc[8][r];
      v8 += __shfl_xor(v8, 8, 64);  // hi + lo at lanes l15<8
      if (ok) {
        if (l15 < 4) a_s[grow * 4 + l15] = v8;
        else if (l15 < 8) a_d[grow * 4 + (l15 - 4)] = v8;
      }
    }
  }
}

// --- scatter into FIXED per-bucket regions; bcnt doubles as cursor (no scan) ---
__global__ __launch_bounds__(1024) void pair_scatter3_k(const int* __restrict__ src,
                                                        const int* __restrict__ dst,
                                                        int* __restrict__ bcnt,
                                                        unsigned* __restrict__ pairs,
                                                        int E, int nb) {
  __shared__ int cnt[1024];
  int t = threadIdx.x;
  int chunk = (E + gridDim.x - 1) / gridDim.x;
  int lo = blockIdx.x * chunk;
  int hi = min(E, lo + chunk);
  for (int i = t; i < nb; i += 1024) cnt[i] = 0;
  __syncthreads();
  for (int i = lo + t; i < hi; i += 1024) atomicAdd(&cnt[dst[i] >> 6], 1);
  __syncthreads();
  for (int i = t; i < nb; i += 1024) {
    int c = cnt[i];
    cnt[i] = c ? atomicAdd(&bcnt[i], c) : 0;  // reserve dense run in bucket region
  }
  __syncthreads();
  for (int i = lo + t; i < hi; i += 1024) {
    int d = dst[i];
    int b = d >> 6;
    int pos = atomicAdd(&cnt[b], 1);
    if (pos < PSTRIDE)
      pairs[(size_t)b * PSTRIDE + pos] = (unsigned)src[i] | ((unsigned)(d & 63) << 26);
  }
}

// --- one block per bucket -> per-dst segments in strided ssrc (+dlen) ---
__global__ __launch_bounds__(256) void bucket_csr_k(const unsigned* __restrict__ pairs,
                                                    const int* __restrict__ bcnt,
                                                    int* __restrict__ off,
                                                    int* __restrict__ dlen,
                                                    int* __restrict__ ssrc, int n) {
  __shared__ int hist[64], lofs[64], curs[64];
  int b = blockIdx.x;
  int t = threadIdx.x;
  int d0 = b << 6;
  int dcnt = min(64, n - d0);
  int cnt = min(bcnt[b], PSTRIDE);
  size_t pstart = (size_t)b * PSTRIDE;
  int ob = b * SSTRIDE;
  if (t < 64) hist[t] = (t < dcnt) ? 1 : 0;  // self-loop seeds count
  __syncthreads();
  for (int i = t; i < cnt; i += 256) atomicAdd(&hist[pairs[pstart + i] >> 26], 1);
  __syncthreads();
  if (t == 0) {
    int acc = 0;
    for (int k = 0; k < 64; k++) { lofs[k] = acc; acc += hist[k]; }
  }
  __syncthreads();
  if (t < dcnt) {
    int lo = lofs[t];
    off[d0 + t] = ob + lo;
    dlen[d0 + t] = hist[t];
    curs[t] = lo + 1;          // slot 0 = self-loop
    ssrc[ob + lo] = d0 + t;    // self-loop entry
  }
  __syncthreads();
  for (int i = t; i < cnt; i += 256) {
    unsigned u = pairs[pstart + i];
    int dl = u >> 26;
    int pos = ob + atomicAdd(&curs[dl], 1);
    ssrc[pos] = (int)(u & 0x03FFFFFFu);
  }
}

// -------- aggregation: one wave per dst, quarter-wave edge groups --------
// lane = 16*q + m. Edge src indices travel via __shfl; first pair-step hb2
// gathers issue BEFORE the a_s+exp chain; 1-deep software pipeline (R15).
// h is fp16-packed: fmaf(__half2float(..)) -> v_fma_mix_f32, no unpack ops.
// BN stats: LDS partials -> ONE 256-atomic volley (NC=32). No threadfence.
#define FMA4(g, p)                                                            \
  alo0 = fmaf(f16lo(g.x), p.x, alo0); ahi0 = fmaf(f16hi(g.x), p.y, ahi0);     \
  alo1 = fmaf(f16lo(g.y), p.x, alo1); ahi1 = fmaf(f16hi(g.y), p.y, ahi1);     \
  alo2 = fmaf(f16lo(g.z), p.x, alo2); ahi2 = fmaf(f16hi(g.z), p.y, ahi2);     \
  alo3 = fmaf(f16lo(g.w), p.x, alo3); ahi3 = fmaf(f16hi(g.w), p.y, ahi3);

__global__ __launch_bounds__(256) void agg_csr_k(const int* __restrict__ off,
                                                 const int* __restrict__ dlen,
                                                 const int* __restrict__ ssrc,
                                                 const float* __restrict__ a_s,
                                                 const float* __restrict__ a_d,
                                                 const unsigned* __restrict__ hb2,
                                                 float* __restrict__ out,
                                                 float* __restrict__ gstat, int n) {
  __shared__ float lp[4][64 * 4];
  __shared__ float bstat[4][256];  // per-wave: sum[128] | sumsq[128]
  int tid = threadIdx.x;
  int wid = tid >> 6;
  int lane = tid & 63;
  int q = lane >> 4;   // quarter: which edge of the 4-group
  int m = lane & 15;   // column group: dwords 4m..4m+3
  int hsel = m >> 3;   // head pair select: heads hsel / hsel+2

  int d = blockIdx.x * 4 + wid;
  bool act = d < n;    // wave-uniform

  float alo0 = 0.f, alo1 = 0.f, alo2 = 0.f, alo3 = 0.f;
  float ahi0 = 0.f, ahi1 = 0.f, ahi2 = 0.f, ahi3 = 0.f;
  float l0 = 0.f, l1 = 0.f, l2 = 0.f, l3 = 0.f;

  if (act) {
    int start = off[d];
    int end = start + dlen[d];
    float4 ad4 = *(const float4*)&a_d[d * 4];
    for (int base = start; base < end; base += 64) {
      int cnt = min(64, end - base);   // wave-uniform
      int j = base + lane;
      int s = ssrc[min(j, end - 1)];   // coalesced; clamped for tail lanes

      // ---- issue first pair-step gathers BEFORE the exp chain ----
      uint4 g0, g1;
      bool pipe = (cnt >= 8);          // wave-uniform
      if (pipe) {
        int s0 = __shfl(s, q, 64);
        int s1 = __shfl(s, 4 + q, 64);
        g0 = *(const uint4*)&hb2[(size_t)s0 * 64 + m * 4];
        g1 = *(const uint4*)&hb2[(size_t)s1 * 64 + m * 4];
      }

      // ---- a_s gather + exp chain (overlaps with g0/g1 in flight) ----
      float4 as4 = *(const float4*)&a_s[s * 4];
      float p0 = __expf(lrelu02(as4.x + ad4.x));
      float p1 = __expf(lrelu02(as4.y + ad4.y));
      float p2 = __expf(lrelu02(as4.z + ad4.z));
      float p3 = __expf(lrelu02(as4.w + ad4.w));
      if (j < end) { l0 += p0; l1 += p1; l2 += p2; l3 += p3; }
      *(float4*)&lp[wid][lane * 4] = make_float4(p0, p2, p1, p3);  // tail slots never read

      // ---- main loop: consume current pair-step, prefetch next ----
      int k = 0;
      for (; k + 16 <= cnt; k += 8) {
        int s0n = __shfl(s, k + 8 + q, 64);
        int s1n = __shfl(s, k + 12 + q, 64);
        uint4 h0 = *(const uint4*)&hb2[(size_t)s0n * 64 + m * 4];
        uint4 h1 = *(const uint4*)&hb2[(size_t)s1n * 64 + m * 4];
        float2 pp0 = *(const float2*)&lp[wid][(k + q) * 4 + hsel * 2];
        float2 pp1 = *(const float2*)&lp[wid][(k + 4 + q) * 4 + hsel * 2];
        FMA4(g0, pp0);
        FMA4(g1, pp1);
        g0 = h0; g1 = h1;
      }
      if (pipe) {  // drain the prefetched step
        float2 pp0 = *(const float2*)&lp[wid][(k + q) * 4 + hsel * 2];
        float2 pp1 = *(const float2*)&lp[wid][(k + 4 + q) * 4 + hsel * 2];
        FMA4(g0, pp0);
        FMA4(g1, pp1);
        k += 8;
      }
      for (; k + 4 <= cnt; k += 4) {
        int s0 = __shfl(s, k + q, 64);
        uint4 g = *(const uint4*)&hb2[(size_t)s0 * 64 + m * 4];
        float2 pp = *(const float2*)&lp[wid][(k + q) * 4 + hsel * 2];
        FMA4(g, pp);
      }
      int rem = cnt - k;
      if (rem > 0) {  // wave-uniform; 1..3 leftover edges
        int e = min(k + q, cnt - 1);
        int s0 = __shfl(s, e, 64);
        uint4 g = *(const uint4*)&hb2[(size_t)s0 * 64 + m * 4];
        float2 pp = *(const float2*)&lp[wid][e * 4 + hsel * 2];
        if (q < rem) { FMA4(g, pp); }
      }
    }
  }

  // merge the 4 quarters' accumulators (same columns, different edges)
#pragma unroll
  for (int o = 16; o < 64; o <<= 1) {
    alo0 += __shfl_xor(alo0, o, 64); alo1 += __shfl_xor(alo1, o, 64);
    alo2 += __shfl_xor(alo2, o, 64); alo3 += __shfl_xor(alo3, o, 64);
    ahi0 += __shfl_xor(ahi0, o, 64); ahi1 += __shfl_xor(ahi1, o, 64);
    ahi2 += __shfl_xor(ahi2, o, 64); ahi3 += __shfl_xor(ahi3, o, 64);
  }
#pragma unroll
  for (int o = 1; o < 64; o <<= 1) {
    l0 += __shfl_xor(l0, o, 64);
    l1 += __shfl_xor(l1, o, 64);
    l2 += __shfl_xor(l2, o, 64);
    l3 += __shfl_xor(l3, o, 64);
  }
  float il_lo = 1.0f / (hsel ? l1 : l0);
  float il_hi = 1.0f / (hsel ? l3 : l2);
  float4 flo = make_float4(0.f, 0.f, 0.f, 0.f);
  float4 fhi = make_float4(0.f, 0.f, 0.f, 0.f);
  if (act) {
    flo = make_float4(alo0 * il_lo, alo1 * il_lo, alo2 * il_lo, alo3 * il_lo);
    fhi = make_float4(ahi0 * il_hi, ahi1 * il_hi, ahi2 * il_hi, ahi3 * il_hi);
  }
  if (q == 0) {
    if (act) {
      *(float4*)&out[(size_t)d * 128 + m * 4] = flo;
      *(float4*)&out[(size_t)d * 128 + 64 + m * 4] = fhi;
    }
    *(float4*)&bstat[wid][m * 4] = flo;
    *(float4*)&bstat[wid][64 + m * 4] = fhi;
    *(float4*)&bstat[wid][128 + m * 4] =
        make_float4(flo.x * flo.x, flo.y * flo.y, flo.z * flo.z, flo.w * flo.w);
    *(float4*)&bstat[wid][192 + m * 4] =
        make_float4(fhi.x * fhi.x, fhi.y * fhi.y, fhi.z * fhi.z, fhi.w * fhi.w);
  }
  __syncthreads();
  float v = bstat[0][tid] + bstat[1][tid] + bstat[2][tid] + bstat[3][tid];
  atomicAdd(&gstat[(blockIdx.x & (NC - 1)) * 256 + tid], v);
}

// ---- reduce NC gstat copies -> BN coefs (sc[128] | sh[128]), ONE block ----
__global__ __launch_bounds__(128) void bn_coef_k(const float* __restrict__ gstat,
                                                 const float* __restrict__ gamma,
                                                 const float* __restrict__ beta,
                                                 float* __restrict__ coef,
                                                 float inv_n) {
  int tid = threadIdx.x;  // 0..127
  float s = 0.f, s2 = 0.f;
#pragma unroll 8
  for (int c = 0; c < NC; c++) {
    s += gstat[c * 256 + tid];
    s2 += gstat[c * 256 + 128 + tid];
  }
  float mu = s * inv_n;
  float var = s2 * inv_n - mu * mu;
  float rstd = 1.0f / sqrtf(var + 1e-5f);
  float g = gamma[tid] * rstd;
  coef[tid] = g;
  coef[128 + tid] = beta[tid] - mu * g;
}

// normalize + LeakyReLU(0.01) using precomputed coefs
__global__ __launch_bounds__(256) void bn_apply_k(float* __restrict__ out,
                                                  const float* __restrict__ coef,
                                                  int n4) {
  __shared__ float sc[128], sh[128];
  int tid = threadIdx.x;
  if (tid < 128) {
    sc[tid] = coef[tid];
    sh[tid] = coef[128 + tid];
  }
  __syncthreads();
  int i = blockIdx.x * 256 + tid;
  if (i >= n4) return;
  float4 v = ((float4*)out)[i];
  int j = (i & 31) << 2;
  const float4 scv = *(const float4*)&sc[j];
  const float4 shv = *(const float4*)&sh[j];
  v.x = fmaf(v.x, scv.x, shv.x);
  v.y = fmaf(v.y, scv.y, shv.y);
  v.z = fmaf(v.z, scv.z, shv.z);
  v.w = fmaf(v.w, scv.w, shv.w);
  v.x = v.x > 0.f ? v.x : 0.01f * v.x;
  v.y = v.y > 0.f ? v.y : 0.01f * v.y;
  v.z = v.z > 0.f ? v.z : 0.01f * v.z;
  v.w = v.w > 0.f ? v.w : 0.01f * v.w;
  ((float4*)out)[i] = v;
}

static inline char* align16(char* p) {
  return (char*)(((uintptr_t)p + 15) & ~(uintptr_t)15);
}

extern "C" void kernel_launch(void* const* d_in, const int* in_sizes, int n_in,
                              void* d_out, int out_size, void* d_ws, size_t ws_size,
                              hipStream_t stream) {
  const float* x     = (const float*)d_in[0];
  const int*   ei    = (const int*)d_in[1];
  const float* W     = (const float*)d_in[2];
  const float* att_s = (const float*)d_in[3];
  const float* att_d = (const float*)d_in[4];
  // d_in[5] = bias: cancels under batch-stat BN
  const float* gamma = (const float*)d_in[6];
  const float* beta  = (const float*)d_in[7];

  int n = in_sizes[0] / 256;
  int E = in_sizes[1] / 2;
  const int* src = ei;
  const int* dstp = ei + E;
  float* out = (float*)d_out;

  int NBUCK = (n + 63) >> 6;   // <= 1024 for n <= 65536
  int ntiles = (n + 63) / 64;

  char* p = (char*)d_ws;
  unsigned* hb2 = (unsigned*)p; p = align16(p + (size_t)n * 64 * 4);
  float* a_s   = (float*)p; p = align16(p + (size_t)n * 4 * 4);
  float* a_d   = (float*)p; p = align16(p + (size_t)n * 4 * 4);
  float* waug  = (float*)p; p = align16(p + 8 * 256 * 4);
  // gstat | coef | bcnt contiguous -> ONE memset
  float* gstat = (float*)p;                    // NC*256 partial copies
  float* coef  = gstat + NC * 256;             // 256 coefs (fully overwritten)
  int*   bcnt  = (int*)(coef + 256);
  p = align16((char*)(bcnt + NBUCK));
  int* off     = (int*)p;   p = align16(p + (size_t)n * 4);
  int* dlen    = (int*)p;   p = align16(p + (size_t)n * 4);
  int* ssrc    = (int*)p;   p = align16(p + (size_t)NBUCK * SSTRIDE * 4);
  unsigned* pairs = (unsigned*)p; p = align16(p + (size_t)NBUCK * PSTRIDE * 4);

  hipMemsetAsync(gstat, 0, ((size_t)NC * 256 + 256 + NBUCK) * 4, stream);

  att_fold_k<<<8, 256, 0, stream>>>(W, att_s, att_d, waug);
  gemm_mfma<<<256, 256, 0, stream>>>(x, W, waug, hb2, a_s, a_d, n, ntiles);

  pair_scatter3_k<<<256, 1024, 0, stream>>>(src, dstp, bcnt, pairs, E, NBUCK);
  bucket_csr_k<<<NBUCK, 256, 0, stream>>>(pairs, bcnt, off, dlen, ssrc, n);

  agg_csr_k<<<(n + 3) / 4, 256, 0, stream>>>(off, dlen, ssrc, a_s, a_d, hb2, out,
                                             gstat, n);

  bn_coef_k<<<1, 128, 0, stream>>>(gstat, gamma, beta, coef, 1.0f / n);
  bn_apply_k<<<(n * 32 + 255) / 256, 256, 0, stream>>>(out, coef, n * 32);
}

// Round 10
// 193.243 us; speedup vs baseline: 1.0077x; 1.0077x over previous
//
#include <hip/hip_runtime.h>
#include <hip/hip_bf16.h>
#include <hip/hip_fp16.h>
#include <math.h>

// F_IN=256, H=4, C=32, H*C=128; NEG_SLOPE_ATT=0.2, NEG_SLOPE_ACT=0.01, EPS=1e-5
// bias skipped: batch-stat BatchNorm subtracts it exactly.
//
// R9: wave-per-dst agg; fixed-stride buckets. 233us.
// R10: __threadfence per block REGRESSED 1248us (per-XCD L2 wb+inv).
// R11: fence-free fused BN (NC-copy atomics). 206us; agg 45.2.
// R12: DPW=4 killed TLP. R13: waug augmented-GEMM (-7us). R14: agg 58us
//      regression = lp/lsrc lgkm serialization, not the inner loop.
// R15/16: shfl-pipelined agg (hb2 gathers overlap a_s+exp). agg 50. 203.9.
// R17: gemm v_cvt_pk staging/epilogue + scatter 256 blocks. 193.9.
// R18: hb2 -> fp16 pairs (cvt_pkrtz + fma_mix consumption). Time-neutral
//      (agg 48.5 @ VALU 51% unchanged -> unpack wasn't marginal cost);
//      absmax 0.0625 -> 0.03125. Keep for precision headroom.
// R19: agg-only: (a) 32-bit gather offsets (hb2 12.8MB, a_s 800KB -> SADDR
//      form, 1-2 VALU/addr vs 4-6 for 64-bit chains); (b) softmax denom
//      fused into FMA path (den += p per edge, merged in existing o=16/32
//      quarter-merge) -> prologue l-adds + 24shfl/24add l-reduction gone.

typedef __attribute__((ext_vector_type(8))) short bf8_t;   // 8 bf16 in 4 VGPRs
typedef __attribute__((ext_vector_type(4))) float f4_t;    // MFMA accumulator

__device__ inline unsigned short f2bf(float f) {  // RNE fp32->bf16
  unsigned u = __float_as_uint(f);
  u += 0x7fff + ((u >> 16) & 1);
  return (unsigned short)(u >> 16);
}
// packed RNE fp32x2 -> bf16x2 (low = a, high = b); gfx950 has no builtin
__device__ inline unsigned cvtpk(float a, float b) {
  unsigned r;
  asm("v_cvt_pk_bf16_f32 %0, %1, %2" : "=v"(r) : "v"(a), "v"(b));
  return r;
}
// packed RTZ fp32x2 -> fp16x2 (low = a, high = b)
__device__ inline unsigned cvtpk_f16(float a, float b) {
  unsigned r;
  asm("v_cvt_pkrtz_f16_f32 %0, %1, %2" : "=v"(r) : "v"(a), "v"(b));
  return r;
}
__device__ inline float lrelu02(float v) { return v > 0.f ? v : 0.2f * v; }
// fp16 halves of a packed dword -> f32 (compiler folds fpext into v_fma_mix)
__device__ inline float f16lo(unsigned g) {
  return __half2float(__ushort_as_half((unsigned short)(g & 0xffffu)));
}
__device__ inline float f16hi(unsigned g) {
  return __half2float(__ushort_as_half((unsigned short)(g >> 16)));
}

#define LSTRIDE 264   // 256 + 8 bf16 pad
#define PSTRIDE 2048  // per-bucket pairs region (max bucket ~1130 = 32 sigma)
#define SSTRIDE 2112  // PSTRIDE + 64 self-loops
#define NC 32         // BN stat atomic copies

// ---- fold attention vectors into augmented GEMM rows ----
__global__ __launch_bounds__(256) void att_fold_k(const float* __restrict__ w,
                                                  const float* __restrict__ att_s,
                                                  const float* __restrict__ att_d,
                                                  float* __restrict__ waug) {
  int j = blockIdx.x;  // 0..7
  int head = j & 3;
  const float* av = (j < 4 ? att_s : att_d) + head * 32;
  int col = threadIdx.x;
  float s = 0.f;
#pragma unroll
  for (int c = 0; c < 32; c++)
    s += av[c] * w[(size_t)(head * 32 + c) * 256 + col];
  waug[j * 256 + col] = s;
}

// ------- MFMA GEMM + att scores as augmented columns -------
// hb2[node][j] (dword) = ( fp16 h[node][j] , fp16 h[node][j+64] )
// B rows 0-127: W; rows 128-135: waug hi; rows 136-143: waug lo.
__global__ __launch_bounds__(256) void gemm_mfma(const float* __restrict__ x,
                                                 const float* __restrict__ w,
                                                 const float* __restrict__ waug,
                                                 unsigned* __restrict__ hb2,
                                                 float* __restrict__ a_s,
                                                 float* __restrict__ a_d,
                                                 int n, int ntiles) {
  __shared__ unsigned short wsl[144 * LSTRIDE];  // 76.0 KB
  __shared__ unsigned short xsl[64 * LSTRIDE];   // 33.8 KB
  int tid = threadIdx.x;
  int lane = tid & 63;
  int wid = tid >> 6;
  int quad = lane >> 4;
  int l15 = lane & 15;

  // stage W once: 128 rows x 64 float4 = 8192 f4, 32/thread
#pragma unroll 4
  for (int i = 0; i < 32; i++) {
    int idx = tid + i * 256;
    int row = idx >> 6;
    int f4 = idx & 63;
    float4 v = *(const float4*)&w[(size_t)row * 256 + f4 * 4];
    *(uint2*)&wsl[row * LSTRIDE + f4 * 4] =
        make_uint2(cvtpk(v.x, v.y), cvtpk(v.z, v.w));
  }
  // stage waug: 8 rows fp32 -> hi (rows 128-135) + lo (rows 136-143)
#pragma unroll
  for (int i = 0; i < 8; i++) {
    int idx = tid + i * 256;   // 0..2047
    int row = idx >> 8;        // 0..7
    int col = idx & 255;
    float v = waug[idx];
    unsigned short hi = f2bf(v);
    float lov = v - __uint_as_float((unsigned)hi << 16);
    wsl[(128 + row) * LSTRIDE + col] = hi;
    wsl[(136 + row) * LSTRIDE + col] = f2bf(lov);
  }

  float4 pre[16];
  int tile = blockIdx.x;
  if (tile < ntiles) {
#pragma unroll
    for (int i = 0; i < 16; i++) {
      int idx = tid + i * 256;
      int row = idx >> 6, f4 = idx & 63;
      int grow = tile * 64 + row;
      pre[i] = (grow < n) ? *(const float4*)&x[(size_t)grow * 256 + f4 * 4]
                          : make_float4(0.f, 0.f, 0.f, 0.f);
    }
  }

  for (; tile < ntiles; tile += gridDim.x) {
    __syncthreads();
#pragma unroll
    for (int i = 0; i < 16; i++) {
      int idx = tid + i * 256;
      int row = idx >> 6, f4 = idx & 63;
      *(uint2*)&xsl[row * LSTRIDE + f4 * 4] =
          make_uint2(cvtpk(pre[i].x, pre[i].y), cvtpk(pre[i].z, pre[i].w));
    }
    __syncthreads();

    int nxt = tile + gridDim.x;
    if (nxt < ntiles) {
#pragma unroll
      for (int i = 0; i < 16; i++) {
        int idx = tid + i * 256;
        int row = idx >> 6, f4 = idx & 63;
        int grow = nxt * 64 + row;
        pre[i] = (grow < n) ? *(const float4*)&x[(size_t)grow * 256 + f4 * 4]
                            : make_float4(0.f, 0.f, 0.f, 0.f);
      }
    }

    f4_t acc[9];
#pragma unroll
    for (int t = 0; t < 9; t++) acc[t] = (f4_t){0.f, 0.f, 0.f, 0.f};
    const unsigned short* arow = &xsl[(wid * 16 + l15) * LSTRIDE];
#pragma unroll
    for (int ks = 0; ks < 8; ks++) {
      bf8_t af = *(const bf8_t*)&arow[ks * 32 + quad * 8];
#pragma unroll
      for (int t = 0; t < 9; t++) {
        bf8_t bf = *(const bf8_t*)&wsl[(t * 16 + l15) * LSTRIDE + ks * 32 + quad * 8];
        acc[t] = __builtin_amdgcn_mfma_f32_16x16x32_bf16(af, bf, acc[t], 0, 0, 0);
      }
    }

    // C/D layout: col = lane&15 (-> t*16+l15), row = quad*4 + reg  [m89-verified]
    int growb = tile * 64 + wid * 16 + quad * 4;
#pragma unroll
    for (int r = 0; r < 4; r++) {
      int grow = growb + r;
      bool ok = grow < n;
      if (ok) {
        unsigned* orow = &hb2[(size_t)grow * 64];
#pragma unroll
        for (int t = 0; t < 4; t++)
          orow[t * 16 + l15] = cvtpk_f16(acc[t][r], acc[t + 4][r]);
      }
      // att columns: lane l15<8 holds hi(col l15); lane l15+8 holds lo
      float v8 = acc[8][r];
      v8 += __shfl_xor(v8, 8, 64);  // hi + lo at lanes l15<8
      if (ok) {
        if (l15 < 4) a_s[grow * 4 + l15] = v8;
        else if (l15 < 8) a_d[grow * 4 + (l15 - 4)] = v8;
      }
    }
  }
}

// --- scatter into FIXED per-bucket regions; bcnt doubles as cursor (no scan) ---
__global__ __launch_bounds__(1024) void pair_scatter3_k(const int* __restrict__ src,
                                                        const int* __restrict__ dst,
                                                        int* __restrict__ bcnt,
                                                        unsigned* __restrict__ pairs,
                                                        int E, int nb) {
  __shared__ int cnt[1024];
  int t = threadIdx.x;
  int chunk = (E + gridDim.x - 1) / gridDim.x;
  int lo = blockIdx.x * chunk;
  int hi = min(E, lo + chunk);
  for (int i = t; i < nb; i += 1024) cnt[i] = 0;
  __syncthreads();
  for (int i = lo + t; i < hi; i += 1024) atomicAdd(&cnt[dst[i] >> 6], 1);
  __syncthreads();
  for (int i = t; i < nb; i += 1024) {
    int c = cnt[i];
    cnt[i] = c ? atomicAdd(&bcnt[i], c) : 0;  // reserve dense run in bucket region
  }
  __syncthreads();
  for (int i = lo + t; i < hi; i += 1024) {
    int d = dst[i];
    int b = d >> 6;
    int pos = atomicAdd(&cnt[b], 1);
    if (pos < PSTRIDE)
      pairs[(size_t)b * PSTRIDE + pos] = (unsigned)src[i] | ((unsigned)(d & 63) << 26);
  }
}

// --- one block per bucket -> per-dst segments in strided ssrc (+dlen) ---
__global__ __launch_bounds__(256) void bucket_csr_k(const unsigned* __restrict__ pairs,
                                                    const int* __restrict__ bcnt,
                                                    int* __restrict__ off,
                                                    int* __restrict__ dlen,
                                                    int* __restrict__ ssrc, int n) {
  __shared__ int hist[64], lofs[64], curs[64];
  int b = blockIdx.x;
  int t = threadIdx.x;
  int d0 = b << 6;
  int dcnt = min(64, n - d0);
  int cnt = min(bcnt[b], PSTRIDE);
  size_t pstart = (size_t)b * PSTRIDE;
  int ob = b * SSTRIDE;
  if (t < 64) hist[t] = (t < dcnt) ? 1 : 0;  // self-loop seeds count
  __syncthreads();
  for (int i = t; i < cnt; i += 256) atomicAdd(&hist[pairs[pstart + i] >> 26], 1);
  __syncthreads();
  if (t == 0) {
    int acc = 0;
    for (int k = 0; k < 64; k++) { lofs[k] = acc; acc += hist[k]; }
  }
  __syncthreads();
  if (t < dcnt) {
    int lo = lofs[t];
    off[d0 + t] = ob + lo;
    dlen[d0 + t] = hist[t];
    curs[t] = lo + 1;          // slot 0 = self-loop
    ssrc[ob + lo] = d0 + t;    // self-loop entry
  }
  __syncthreads();
  for (int i = t; i < cnt; i += 256) {
    unsigned u = pairs[pstart + i];
    int dl = u >> 26;
    int pos = ob + atomicAdd(&curs[dl], 1);
    ssrc[pos] = (int)(u & 0x03FFFFFFu);
  }
}

// -------- aggregation: one wave per dst, quarter-wave edge groups --------
// lane = 16*q + m. Edge src indices via __shfl; first pair-step hb2 gathers
// issue BEFORE the a_s+exp chain; 1-deep software pipeline (R15).
// 32-bit gather offsets (SADDR form); softmax denominator accumulated in
// the FMA path (dlo/dhi) and merged with the o=16/32 quarter-merge -- no
// separate l-reduction. h fp16-packed (fma_mix). BN stats: LDS partials ->
// ONE 256-atomic volley (NC=32). No threadfence (R10 lesson).
#define FMA4(g, p)                                                            \
  alo0 = fmaf(f16lo(g.x), p.x, alo0); ahi0 = fmaf(f16hi(g.x), p.y, ahi0);     \
  alo1 = fmaf(f16lo(g.y), p.x, alo1); ahi1 = fmaf(f16hi(g.y), p.y, ahi1);     \
  alo2 = fmaf(f16lo(g.z), p.x, alo2); ahi2 = fmaf(f16hi(g.z), p.y, ahi2);     \
  alo3 = fmaf(f16lo(g.w), p.x, alo3); ahi3 = fmaf(f16hi(g.w), p.y, ahi3);     \
  dlo += p.x; dhi += p.y;

__global__ __launch_bounds__(256) void agg_csr_k(const int* __restrict__ off,
                                                 const int* __restrict__ dlen,
                                                 const int* __restrict__ ssrc,
                                                 const float* __restrict__ a_s,
                                                 const float* __restrict__ a_d,
                                                 const unsigned* __restrict__ hb2,
                                                 float* __restrict__ out,
                                                 float* __restrict__ gstat, int n) {
  __shared__ float lp[4][64 * 4];
  __shared__ float bstat[4][256];  // per-wave: sum[128] | sumsq[128]
  int tid = threadIdx.x;
  int wid = tid >> 6;
  int lane = tid & 63;
  int q = lane >> 4;   // quarter: which edge of the 4-group
  int m = lane & 15;   // column group: dwords 4m..4m+3
  int hsel = m >> 3;   // head pair select: heads hsel / hsel+2
  unsigned mo = (unsigned)m * 4u;  // column dword offset

  int d = blockIdx.x * 4 + wid;
  bool act = d < n;    // wave-uniform

  float alo0 = 0.f, alo1 = 0.f, alo2 = 0.f, alo3 = 0.f;
  float ahi0 = 0.f, ahi1 = 0.f, ahi2 = 0.f, ahi3 = 0.f;
  float dlo = 0.f, dhi = 0.f;  // softmax denominators (heads hsel, hsel+2)

  if (act) {
    int start = off[d];
    int end = start + dlen[d];
    float4 ad4 = *(const float4*)&a_d[(unsigned)d * 4u];
    for (int base = start; base < end; base += 64) {
      int cnt = min(64, end - base);   // wave-uniform
      int j = base + lane;
      int s = ssrc[(unsigned)min(j, end - 1)];  // coalesced; clamped tail

      // ---- issue first pair-step gathers BEFORE the exp chain ----
      uint4 g0, g1;
      bool pipe = (cnt >= 8);          // wave-uniform
      if (pipe) {
        unsigned s0 = (unsigned)__shfl(s, q, 64);
        unsigned s1 = (unsigned)__shfl(s, 4 + q, 64);
        g0 = *(const uint4*)&hb2[s0 * 64u + mo];
        g1 = *(const uint4*)&hb2[s1 * 64u + mo];
      }

      // ---- a_s gather + exp chain (overlaps with g0/g1 in flight) ----
      float4 as4 = *(const float4*)&a_s[(unsigned)s * 4u];
      float p0 = __expf(lrelu02(as4.x + ad4.x));
      float p1 = __expf(lrelu02(as4.y + ad4.y));
      float p2 = __expf(lrelu02(as4.z + ad4.z));
      float p3 = __expf(lrelu02(as4.w + ad4.w));
      *(float4*)&lp[wid][lane * 4] = make_float4(p0, p2, p1, p3);  // tail slots never read

      // ---- main loop: consume current pair-step, prefetch next ----
      int k = 0;
      for (; k + 16 <= cnt; k += 8) {
        unsigned s0n = (unsigned)__shfl(s, k + 8 + q, 64);
        unsigned s1n = (unsigned)__shfl(s, k + 12 + q, 64);
        uint4 h0 = *(const uint4*)&hb2[s0n * 64u + mo];
        uint4 h1 = *(const uint4*)&hb2[s1n * 64u + mo];
        float2 pp0 = *(const float2*)&lp[wid][(k + q) * 4 + hsel * 2];
        float2 pp1 = *(const float2*)&lp[wid][(k + 4 + q) * 4 + hsel * 2];
        FMA4(g0, pp0);
        FMA4(g1, pp1);
        g0 = h0; g1 = h1;
      }
      if (pipe) {  // drain the prefetched step
        float2 pp0 = *(const float2*)&lp[wid][(k + q) * 4 + hsel * 2];
        float2 pp1 = *(const float2*)&lp[wid][(k + 4 + q) * 4 + hsel * 2];
        FMA4(g0, pp0);
        FMA4(g1, pp1);
        k += 8;
      }
      for (; k + 4 <= cnt; k += 4) {
        unsigned s0 = (unsigned)__shfl(s, k + q, 64);
        uint4 g = *(const uint4*)&hb2[s0 * 64u + mo];
        float2 pp = *(const float2*)&lp[wid][(k + q) * 4 + hsel * 2];
        FMA4(g, pp);
      }
      int rem = cnt - k;
      if (rem > 0) {  // wave-uniform; 1..3 leftover edges
        int e = min(k + q, cnt - 1);
        unsigned s0 = (unsigned)__shfl(s, e, 64);
        uint4 g = *(const uint4*)&hb2[s0 * 64u + mo];
        float2 pp = *(const float2*)&lp[wid][e * 4 + hsel * 2];
        if (q < rem) { FMA4(g, pp); }
      }
    }
  }

  // merge the 4 quarters' accumulators (same columns, different edges);
  // dlo/dhi merge to the full-edge-set softmax denominators.
#pragma unroll
  for (int o = 16; o < 64; o <<= 1) {
    alo0 += __shfl_xor(alo0, o, 64); alo1 += __shfl_xor(alo1, o, 64);
    alo2 += __shfl_xor(alo2, o, 64); alo3 += __shfl_xor(alo3, o, 64);
    ahi0 += __shfl_xor(ahi0, o, 64); ahi1 += __shfl_xor(ahi1, o, 64);
    ahi2 += __shfl_xor(ahi2, o, 64); ahi3 += __shfl_xor(ahi3, o, 64);
    dlo += __shfl_xor(dlo, o, 64);   dhi += __shfl_xor(dhi, o, 64);
  }
  float il_lo = 1.0f / dlo;
  float il_hi = 1.0f / dhi;
  float4 flo = make_float4(0.f, 0.f, 0.f, 0.f);
  float4 fhi = make_float4(0.f, 0.f, 0.f, 0.f);
  if (act) {
    flo = make_float4(alo0 * il_lo, alo1 * il_lo, alo2 * il_lo, alo3 * il_lo);
    fhi = make_float4(ahi0 * il_hi, ahi1 * il_hi, ahi2 * il_hi, ahi3 * il_hi);
  }
  if (q == 0) {
    if (act) {
      *(float4*)&out[(unsigned)d * 128u + m * 4] = flo;
      *(float4*)&out[(unsigned)d * 128u + 64 + m * 4] = fhi;
    }
    *(float4*)&bstat[wid][m * 4] = flo;
    *(float4*)&bstat[wid][64 + m * 4] = fhi;
    *(float4*)&bstat[wid][128 + m * 4] =
        make_float4(flo.x * flo.x, flo.y * flo.y, flo.z * flo.z, flo.w * flo.w);
    *(float4*)&bstat[wid][192 + m * 4] =
        make_float4(fhi.x * fhi.x, fhi.y * fhi.y, fhi.z * fhi.z, fhi.w * fhi.w);
  }
  __syncthreads();
  float v = bstat[0][tid] + bstat[1][tid] + bstat[2][tid] + bstat[3][tid];
  atomicAdd(&gstat[(blockIdx.x & (NC - 1)) * 256 + tid], v);
}

// ---- reduce NC gstat copies -> BN coefs (sc[128] | sh[128]), ONE block ----
__global__ __launch_bounds__(128) void bn_coef_k(const float* __restrict__ gstat,
                                                 const float* __restrict__ gamma,
                                                 const float* __restrict__ beta,
                                                 float* __restrict__ coef,
                                                 float inv_n) {
  int tid = threadIdx.x;  // 0..127
  float s = 0.f, s2 = 0.f;
#pragma unroll 8
  for (int c = 0; c < NC; c++) {
    s += gstat[c * 256 + tid];
    s2 += gstat[c * 256 + 128 + tid];
  }
  float mu = s * inv_n;
  float var = s2 * inv_n - mu * mu;
  float rstd = 1.0f / sqrtf(var + 1e-5f);
  float g = gamma[tid] * rstd;
  coef[tid] = g;
  coef[128 + tid] = beta[tid] - mu * g;
}

// normalize + LeakyReLU(0.01) using precomputed coefs
__global__ __launch_bounds__(256) void bn_apply_k(float* __restrict__ out,
                                                  const float* __restrict__ coef,
                                                  int n4) {
  __shared__ float sc[128], sh[128];
  int tid = threadIdx.x;
  if (tid < 128) {
    sc[tid] = coef[tid];
    sh[tid] = coef[128 + tid];
  }
  __syncthreads();
  int i = blockIdx.x * 256 + tid;
  if (i >= n4) return;
  float4 v = ((float4*)out)[i];
  int j = (i & 31) << 2;
  const float4 scv = *(const float4*)&sc[j];
  const float4 shv = *(const float4*)&sh[j];
  v.x = fmaf(v.x, scv.x, shv.x);
  v.y = fmaf(v.y, scv.y, shv.y);
  v.z = fmaf(v.z, scv.z, shv.z);
  v.w = fmaf(v.w, scv.w, shv.w);
  v.x = v.x > 0.f ? v.x : 0.01f * v.x;
  v.y = v.y > 0.f ? v.y : 0.01f * v.y;
  v.z = v.z > 0.f ? v.z : 0.01f * v.z;
  v.w = v.w > 0.f ? v.w : 0.01f * v.w;
  ((float4*)out)[i] = v;
}

static inline char* align16(char* p) {
  return (char*)(((uintptr_t)p + 15) & ~(uintptr_t)15);
}

extern "C" void kernel_launch(void* const* d_in, const int* in_sizes, int n_in,
                              void* d_out, int out_size, void* d_ws, size_t ws_size,
                              hipStream_t stream) {
  const float* x     = (const float*)d_in[0];
  const int*   ei    = (const int*)d_in[1];
  const float* W     = (const float*)d_in[2];
  const float* att_s = (const float*)d_in[3];
  const float* att_d = (const float*)d_in[4];
  // d_in[5] = bias: cancels under batch-stat BN
  const float* gamma = (const float*)d_in[6];
  const float* beta  = (const float*)d_in[7];

  int n = in_sizes[0] / 256;
  int E = in_sizes[1] / 2;
  const int* src = ei;
  const int* dstp = ei + E;
  float* out = (float*)d_out;

  int NBUCK = (n + 63) >> 6;   // <= 1024 for n <= 65536
  int ntiles = (n + 63) / 64;

  char* p = (char*)d_ws;
  unsigned* hb2 = (unsigned*)p; p = align16(p + (size_t)n * 64 * 4);
  float* a_s   = (float*)p; p = align16(p + (size_t)n * 4 * 4);
  float* a_d   = (float*)p; p = align16(p + (size_t)n * 4 * 4);
  float* waug  = (float*)p; p = align16(p + 8 * 256 * 4);
  // gstat | coef | bcnt contiguous -> ONE memset
  float* gstat = (float*)p;                    // NC*256 partial copies
  float* coef  = gstat + NC * 256;             // 256 coefs (fully overwritten)
  int*   bcnt  = (int*)(coef + 256);
  p = align16((char*)(bcnt + NBUCK));
  int* off     = (int*)p;   p = align16(p + (size_t)n * 4);
  int* dlen    = (int*)p;   p = align16(p + (size_t)n * 4);
  int* ssrc    = (int*)p;   p = align16(p + (size_t)NBUCK * SSTRIDE * 4);
  unsigned* pairs = (unsigned*)p; p = align16(p + (size_t)NBUCK * PSTRIDE * 4);

  hipMemsetAsync(gstat, 0, ((size_t)NC * 256 + 256 + NBUCK) * 4, stream);

  att_fold_k<<<8, 256, 0, stream>>>(W, att_s, att_d, waug);
  gemm_mfma<<<256, 256, 0, stream>>>(x, W, waug, hb2, a_s, a_d, n, ntiles);

  pair_scatter3_k<<<256, 1024, 0, stream>>>(src, dstp, bcnt, pairs, E, NBUCK);
  bucket_csr_k<<<NBUCK, 256, 0, stream>>>(pairs, bcnt, off, dlen, ssrc, n);

  agg_csr_k<<<(n + 3) / 4, 256, 0, stream>>>(off, dlen, ssrc, a_s, a_d, hb2, out,
                                             gstat, n);

  bn_coef_k<<<1, 128, 0, stream>>>(gstat, gamma, beta, coef, 1.0f / n);
  bn_apply_k<<<(n * 32 + 255) / 256, 256, 0, stream>>>(out, coef, n * 32);
}